// Round 10
// baseline (238.937 us; speedup 1.0000x reference)
//
#include <hip/hip_runtime.h>

#define DD 128
#define NNODES 50000
#define NEDGES 800000
#define BN_EPS 1e-5f
#define NB1 ((NEDGES + 4095) / 4096)       // 196 edge-slice blocks
#define NGROUPS ((NNODES + 255) / 256)     // 196 row-groups (256 rows each)
#define NBLK_SCAN NGROUPS

typedef float f32x4 __attribute__((ext_vector_type(4)));
typedef short bf16x8 __attribute__((ext_vector_type(8)));

__device__ __forceinline__ unsigned short f2bf(float f) {
    unsigned u = __float_as_uint(f);
    u = (u + 0x7FFFu + ((u >> 16) & 1u)) >> 16;   // RNE
    return (unsigned short)u;
}
__device__ __forceinline__ float bf2f(unsigned short s) {
    return __uint_as_float((unsigned)s << 16);
}
__device__ __forceinline__ unsigned packbf(float a, float b) {
    return (unsigned)f2bf(a) | ((unsigned)f2bf(b) << 16);
}
__device__ __forceinline__ float lo_bf(unsigned u) { return __uint_as_float(u << 16); }
__device__ __forceinline__ float hi_bf(unsigned u) { return __uint_as_float(u & 0xFFFF0000u); }

// async global->LDS, 16B per lane; LDS dest = wave-uniform base + lane*16
__device__ __forceinline__ void gload_lds16(const void* g, void* l) {
    __builtin_amdgcn_global_load_lds(
        (const __attribute__((address_space(1))) unsigned int*)g,
        (__attribute__((address_space(3))) unsigned int*)l, 16, 0, 0);
}

// ---------------------------------------------------------------------------
// K1: per-block bucket counts (LDS histogram, no global atomics, no memset)
// + x->bf16 convert. pbase[b][t] = #edges in slice b with row>>8 == t.
// ---------------------------------------------------------------------------
__global__ __launch_bounds__(256) void count_convx_kernel(
    const int* __restrict__ row, int* __restrict__ pbase,
    const float* __restrict__ x, unsigned* __restrict__ h16u,
    int nedges, int npairs)
{
    const int bid = blockIdx.x;
    if (bid < NB1) {
        __shared__ int cnt[256];
        cnt[threadIdx.x] = 0;
        __syncthreads();
        const int estart = bid * 4096;
        const int eend = min(estart + 4096, nedges);
        for (int e = estart + threadIdx.x; e < eend; e += 256)
            atomicAdd(&cnt[row[e] >> 8], 1);          // LDS atomic
        __syncthreads();
        pbase[bid * 256 + threadIdx.x] = cnt[threadIdx.x];
    } else {
        int stride = (gridDim.x - NB1) * 256;
        for (int i = (bid - NB1) * 256 + threadIdx.x; i < npairs; i += stride) {
            float2 v = ((const float2*)x)[i];
            h16u[i] = packbf(v.x, v.y);
        }
    }
}

// ---------------------------------------------------------------------------
// K2: block 0: column-scan pbase in place -> per-(block,bucket) offsets;
// LDS-scan bucket totals -> bktbase[257]; rowptr[N]=NEDGES.
// Blocks 1..48: weight->fragment convert.
// Wf: [li][ks][nt][lane][i] bf16; value = B[k][n],
//     k = ks*32+(lane>>4)*8+i (k<128 -> W else SW), n = nt*16+(lane&15)
// ---------------------------------------------------------------------------
__global__ __launch_bounds__(256) void scanall_convwf_kernel(
    int* __restrict__ pbase, int* __restrict__ bktbase, int* __restrict__ rowptr,
    const float* __restrict__ W, const float* __restrict__ SW,
    unsigned short* __restrict__ Wf)
{
    if (blockIdx.x == 0) {
        __shared__ int buf[256];
        const int t = threadIdx.x;
        int s = 0;
#pragma unroll 4
        for (int blk = 0; blk < NB1; ++blk) {
            int tmp = pbase[blk * 256 + t];
            pbase[blk * 256 + t] = s;
            s += tmp;
        }
        const int v = s;                  // bucket total
        buf[t] = v;
        __syncthreads();
#pragma unroll
        for (int off = 1; off < 256; off <<= 1) {
            int tv = (t >= off) ? buf[t - off] : 0;
            __syncthreads();
            buf[t] += tv;
            __syncthreads();
        }
        bktbase[t] = buf[t] - v;          // exclusive
        if (t == 255) bktbase[256] = buf[255];
        if (t == 0) rowptr[NNODES] = NEDGES;
        return;
    }
    int t = (blockIdx.x - 1) * 256 + threadIdx.x;   // 12288 total
    if (t < 3 * 8 * 8 * 64) {
        int lane = t & 63;
        int nt   = (t >> 6) & 7;
        int ks   = (t >> 9) & 7;
        int li   = t >> 12;
        const int lmap[3] = {0, 2, 5};
        int l = lmap[li];
        int nn = nt * 16 + (lane & 15);
        unsigned short* dst = Wf + (((size_t)li * 64 + ks * 8 + nt) * 64 + lane) * 8;
#pragma unroll
        for (int i = 0; i < 8; ++i) {
            int k = ks * 32 + (lane >> 4) * 8 + i;
            float v = (k < 128) ? W[((size_t)l * 128 + k) * 128 + nn]
                                : SW[((size_t)l * 128 + (k - 128)) * 128 + nn];
            dst[i] = f2bf(v);
        }
    }
}

// ---------------------------------------------------------------------------
// K3: bin edges into contiguous per-bucket streams (zero global atomics).
// Record: {payload = col | w_bf16<<16, rlow = row & 255} (8B).
// ---------------------------------------------------------------------------
__global__ __launch_bounds__(256) void sort_pass1_kernel(
    const int* __restrict__ row, const int* __restrict__ col,
    const float* __restrict__ ew, const int* __restrict__ pbase,
    const int* __restrict__ bktbase, uint2* __restrict__ inter, int nedges)
{
    __shared__ int base[256];
    __shared__ int cnt[256];
    base[threadIdx.x] = pbase[blockIdx.x * 256 + threadIdx.x] + bktbase[threadIdx.x];
    cnt[threadIdx.x] = 0;
    __syncthreads();
    const int estart = blockIdx.x * 4096;
    const int eend = min(estart + 4096, nedges);
    for (int e = estart + threadIdx.x; e < eend; e += 256) {
        int r = row[e];
        int b = r >> 8;
        int k = atomicAdd(&cnt[b], 1);    // LDS atomic
        unsigned payload = (unsigned)col[e] | ((unsigned)f2bf(ew[e]) << 16);
        inter[base[b] + k] = make_uint2(payload, (unsigned)(r & 255));
    }
}

// ---------------------------------------------------------------------------
// K4: one block per 256-row group. LDS-hist rlow -> LDS scan -> rowptr for
// this group; then windowed scatter into the group's 16KB cedge slice.
// ---------------------------------------------------------------------------
__global__ __launch_bounds__(256) void sort_pass2_kernel(
    const int* __restrict__ bktbase, const uint2* __restrict__ inter,
    int* __restrict__ rowptr, unsigned* __restrict__ cedge, int n)
{
    __shared__ int cnt[256];
    __shared__ int cur[256];
    const int g = blockIdx.x;
    const int rows0 = g * 256;
    const int jbeg = bktbase[g];
    const int jend = bktbase[g + 1];
    cnt[threadIdx.x] = 0;
    __syncthreads();
    for (int j = jbeg + threadIdx.x; j < jend; j += 256)
        atomicAdd(&cnt[inter[j].y], 1);   // LDS atomic
    __syncthreads();
    const int v = cnt[threadIdx.x];
    __syncthreads();
#pragma unroll
    for (int off = 1; off < 256; off <<= 1) {
        int t = (threadIdx.x >= off) ? cnt[threadIdx.x - off] : 0;
        __syncthreads();
        cnt[threadIdx.x] += t;
        __syncthreads();
    }
    const int rp = jbeg + cnt[threadIdx.x] - v;   // exclusive prefix
    if (rows0 + threadIdx.x < n) rowptr[rows0 + threadIdx.x] = rp;
    cur[threadIdx.x] = rp;
    __syncthreads();
    for (int j = jbeg + threadIdx.x; j < jend; j += 256) {
        uint2 rec = inter[j];
        int p = atomicAdd(&cur[rec.y], 1);        // LDS atomic
        cedge[p] = rec.x;
    }
}

// ---------------------------------------------------------------------------
// Fused layer kernel (v2 -- parallelism-preserving, unlike round 4):
//  - issue async gload_lds of the tile's 64 h rows -> As_h (overlaps gather)
//  - gather: 16 quarters x 4 nodes each; 16-lane quarter owns ONE node at a
//    time (lane = 8 cols, uint4 row reads, 4-deep unroll => 64 rows in
//    flight/block); accumulate in regs; pack bf16; ds_write into As_agg.
//    No cross-lane reduction needed.
//  - barrier; MFMA K=256 (ks<4 from As_agg, ks>=4 from As_h)
//  - epilogue BN+relu+residual (residual from As_h); write h_out bf16
//    (ping-pong, no cross-block RAW) or f32 out on last layer.
// ---------------------------------------------------------------------------
__global__ __launch_bounds__(256) void layer_fused_kernel(
    const unsigned short* __restrict__ h_in,   // [n][128] bf16
    unsigned short* __restrict__ h_out,        // [n][128] bf16
    const int* __restrict__ rowptr,
    const unsigned* __restrict__ ce,
    const unsigned short* __restrict__ Wf,     // this layer's 32768 ushorts
    const float* __restrict__ bl, const float* __restrict__ gammal,
    const float* __restrict__ betal, const float* __restrict__ rmeanl,
    const float* __restrict__ rvarl,
    float* __restrict__ outf, int n, int write_f32)
{
    __shared__ __align__(16) unsigned short As_agg[64 * 128];   // 16 KB
    __shared__ __align__(16) unsigned short As_h[64 * 128];     // 16 KB
    const int tid   = threadIdx.x;
    const int lane  = tid & 63;
    const int wid   = tid >> 6;
    const int wbase = tid & 192;          // wave-uniform: wid*64
    const int brow  = blockIdx.x * 64;

    // ---- 1) async stage h rows -> As_h (linear dest, inv-swizzled source) ----
#pragma unroll
    for (int it = 0; it < 4; ++it) {
        const int base_id = it * 256 + wbase;     // wave-uniform 16B-slot base
        const int id  = base_id + lane;           // 0..1023
        const int r   = id >> 4;                  // 0..63
        const int kcs = id & 15;                  // LDS chunk slot
        const int kc  = kcs ^ (r & 7);            // inverse swizzle on SOURCE
        // OOB rows read garbage inside ws (discarded later) -- keep all lanes
        // active so gload_lds lane mapping is unambiguous.
        const unsigned short* src = h_in + (size_t)(brow + r) * DD + kc * 8;
        gload_lds16(src, &As_h[base_id * 8]);
    }

    // ---- 2) gather into As_agg: quarter Q owns rows Q*4..Q*4+3 ----
    {
        const int Q   = wid * 4 + (lane >> 4);    // 0..15
        const int l16 = lane & 15;
        const uint4* __restrict__ h4 = (const uint4*)h_in;
        for (int i = 0; i < 4; ++i) {
            const int r = Q * 4 + i;
            const int node = brow + r;
            if (node < n) {
                const int beg = rowptr[node];
                const int end = rowptr[node + 1];
                float a0 = 0.f, a1 = 0.f, a2 = 0.f, a3 = 0.f;
                float a4 = 0.f, a5 = 0.f, a6 = 0.f, a7 = 0.f;
                int j = beg;
                for (; j + 3 < end; j += 4) {
                    unsigned e0 = ce[j], e1 = ce[j+1], e2 = ce[j+2], e3 = ce[j+3];
                    uint4 v0 = h4[(size_t)(e0 & 0xFFFFu) * 16 + l16];
                    uint4 v1 = h4[(size_t)(e1 & 0xFFFFu) * 16 + l16];
                    uint4 v2 = h4[(size_t)(e2 & 0xFFFFu) * 16 + l16];
                    uint4 v3 = h4[(size_t)(e3 & 0xFFFFu) * 16 + l16];
                    float w0 = bf2f((unsigned short)(e0 >> 16));
                    float w1 = bf2f((unsigned short)(e1 >> 16));
                    float w2 = bf2f((unsigned short)(e2 >> 16));
                    float w3 = bf2f((unsigned short)(e3 >> 16));
                    a0 += w0*lo_bf(v0.x) + w1*lo_bf(v1.x) + w2*lo_bf(v2.x) + w3*lo_bf(v3.x);
                    a1 += w0*hi_bf(v0.x) + w1*hi_bf(v1.x) + w2*hi_bf(v2.x) + w3*hi_bf(v3.x);
                    a2 += w0*lo_bf(v0.y) + w1*lo_bf(v1.y) + w2*lo_bf(v2.y) + w3*lo_bf(v3.y);
                    a3 += w0*hi_bf(v0.y) + w1*hi_bf(v1.y) + w2*hi_bf(v2.y) + w3*hi_bf(v3.y);
                    a4 += w0*lo_bf(v0.z) + w1*lo_bf(v1.z) + w2*lo_bf(v2.z) + w3*lo_bf(v3.z);
                    a5 += w0*hi_bf(v0.z) + w1*hi_bf(v1.z) + w2*hi_bf(v2.z) + w3*hi_bf(v3.z);
                    a6 += w0*lo_bf(v0.w) + w1*lo_bf(v1.w) + w2*lo_bf(v2.w) + w3*lo_bf(v3.w);
                    a7 += w0*hi_bf(v0.w) + w1*hi_bf(v1.w) + w2*hi_bf(v2.w) + w3*hi_bf(v3.w);
                }
                for (; j < end; ++j) {
                    unsigned e = ce[j];
                    uint4 v = h4[(size_t)(e & 0xFFFFu) * 16 + l16];
                    float w = bf2f((unsigned short)(e >> 16));
                    a0 += w * lo_bf(v.x); a1 += w * hi_bf(v.x);
                    a2 += w * lo_bf(v.y); a3 += w * hi_bf(v.y);
                    a4 += w * lo_bf(v.z); a5 += w * hi_bf(v.z);
                    a6 += w * lo_bf(v.w); a7 += w * hi_bf(v.w);
                }
                *(uint4*)&As_agg[r * 128 + ((l16 ^ (r & 7)) << 3)] =
                    make_uint4(packbf(a0, a1), packbf(a2, a3),
                               packbf(a4, a5), packbf(a6, a7));
            }
        }
    }

    // ---- 3) B-fragment prefetch (L2-hot; loads drain at the barrier) ----
    bf16x8 bfr[8][2];
#pragma unroll
    for (int ks = 0; ks < 8; ++ks)
#pragma unroll
        for (int nt2 = 0; nt2 < 2; ++nt2) {
            int nt = wid * 2 + nt2;
            bfr[ks][nt2] = *(const bf16x8*)(Wf + ((size_t)(ks * 8 + nt) * 64 + lane) * 8);
        }
    __syncthreads();

    // ---- 4) MFMA: 8 ksteps x 4 m-tiles x 2 n-tiles ----
    f32x4 acc[4][2];
#pragma unroll
    for (int i = 0; i < 4; ++i)
#pragma unroll
        for (int j = 0; j < 2; ++j)
            acc[i][j] = (f32x4){0.f, 0.f, 0.f, 0.f};

#pragma unroll
    for (int ks = 0; ks < 8; ++ks) {
#pragma unroll
        for (int mt = 0; mt < 4; ++mt) {
            int m  = mt * 16 + (lane & 15);
            int kc = (ks & 3) * 4 + (lane >> 4);   // 0..15 within half
            int kcs = kc ^ (m & 7);
            const unsigned short* Asrc = (ks < 4) ? As_agg : As_h;
            bf16x8 afr = *(const bf16x8*)(&Asrc[m * 128 + (kcs << 3)]);
            acc[mt][0] = __builtin_amdgcn_mfma_f32_16x16x32_bf16(afr, bfr[ks][0], acc[mt][0], 0, 0, 0);
            acc[mt][1] = __builtin_amdgcn_mfma_f32_16x16x32_bf16(afr, bfr[ks][1], acc[mt][1], 0, 0, 0);
        }
    }

    // ---- 5) epilogue: BN + relu + residual (from As_h) ----
#pragma unroll
    for (int nt2 = 0; nt2 < 2; ++nt2) {
        const int gcol = wid * 32 + nt2 * 16 + (lane & 15);
        const float sc = gammal[gcol] * __frsqrt_rn(rvarl[gcol] + BN_EPS);
        const float sh = (bl[gcol] - rmeanl[gcol]) * sc + betal[gcol];
        const int kc_res = gcol >> 3;
        const int ko_res = gcol & 7;
#pragma unroll
        for (int mt = 0; mt < 4; ++mt) {
#pragma unroll
            for (int r = 0; r < 4; ++r) {
                int m = mt * 16 + (lane >> 4) * 4 + r;
                int grow = brow + m;
                if (grow < n) {
                    float res = bf2f(As_h[m * 128 + ((kc_res ^ (m & 7)) << 3) + ko_res]);
                    float t = acc[mt][nt2][r] * sc + sh;
                    float o = res + (t > 0.f ? t : 0.f);
                    if (write_f32) outf[(size_t)grow * DD + gcol] = o;
                    else           h_out[(size_t)grow * DD + gcol] = f2bf(o);
                }
            }
        }
    }
}

extern "C" void kernel_launch(void* const* d_in, const int* in_sizes, int n_in,
                              void* d_out, int out_size, void* d_ws, size_t ws_size,
                              hipStream_t stream) {
    const float* x     = (const float*)d_in[0];
    const int*   row   = (const int*)  d_in[1];
    const int*   col   = (const int*)  d_in[2];
    const float* ew    = (const float*)d_in[3];
    const float* W     = (const float*)d_in[4];
    const float* SW    = (const float*)d_in[5];
    const float* b     = (const float*)d_in[6];
    const float* gamma = (const float*)d_in[7];
    const float* beta  = (const float*)d_in[8];
    const float* rmean = (const float*)d_in[9];
    const float* rvar  = (const float*)d_in[10];

    float* out = (float*)d_out;

    // workspace layout
    char* ws = (char*)d_ws;
    unsigned short* hA    = (unsigned short*)ws;                  // 12.8 MB
    unsigned short* hB    = (unsigned short*)(ws + 12800000);     // 12.8 MB
    unsigned short* Wf    = (unsigned short*)(ws + 25600000);     // 196608 B
    int*   rowptr  = (int*)(ws + 25800000);                       // 50001 ints
    int*   pbase   = (int*)(ws + 26010000);                       // 196*256 ints
    int*   bktbase = (int*)(ws + 26220000);                       // 257 ints
    unsigned* cedge = (unsigned*)(ws + 26400000);                 // 3.2 MB
    uint2*    inter = (uint2*)(ws + 29600000);                    // 6.4 MB

    // ---- build CSR (zero global atomics, no memset) ----
    count_convx_kernel<<<NB1 + 2048, 256, 0, stream>>>(
        row, pbase, x, (unsigned*)hA, NEDGES, NNODES * 64);
    scanall_convwf_kernel<<<1 + 48, 256, 0, stream>>>(
        pbase, bktbase, rowptr, W, SW, Wf);
    sort_pass1_kernel<<<NB1, 256, 0, stream>>>(
        row, col, ew, pbase, bktbase, inter, NEDGES);
    sort_pass2_kernel<<<NGROUPS, 256, 0, stream>>>(
        bktbase, inter, rowptr, cedge, NNODES);

    // Only layers 0, 2, 5 are live (inner branch layers all consume the
    // branch input, so only each branch's last layer reaches the output).
    const int mgrid = (NNODES + 63) / 64;     // 782

    const unsigned short* hin = hA;
    unsigned short* hout = hB;
    for (int li = 0; li < 3; ++li) {
        const int l = (li == 0) ? 0 : (li == 1) ? 2 : 5;
        layer_fused_kernel<<<mgrid, 256, 0, stream>>>(
            hin, hout, rowptr, cedge,
            Wf + (size_t)li * 32768,
            b + l * DD, gamma + l * DD, beta + l * DD, rmean + l * DD, rvar + l * DD,
            out, NNODES, li == 2 ? 1 : 0);
        const unsigned short* t = hin; hin = hout; hout = (unsigned short*)t;
    }
}